// Round 9
// baseline (73.108 us; speedup 1.0000x reference)
//
#include <hip/hip_runtime.h>
#include <type_traits>

typedef float v2f __attribute__((ext_vector_type(2)));

// constant address space -> backend emits s_load (scalar pipe, SGPR return)
template <typename T>
using cptr = T __attribute__((address_space(4)))*;

constexpr int BLOCK = 256;          // 4 waves; wave w owns lags {2w, 2w+1}
constexpr int SPB = 128;            // samples per block (2 per lane)
constexpr int HALO_LO = 10;         // l_max(7) + m_max(3)
constexpr int HALO_HI = 3;          // +m_max for the c (leading) term
constexpr int SIG = SPB + HALO_LO + HALO_HI;   // 141

// ---------------- compile-time unroll helper ----------------
template<int I, int N, typename F>
__device__ __forceinline__ void unroll_for(F&& f) {
    if constexpr (I < N) {
        f(std::integral_constant<int, I>{});
        unroll_for<I + 1, N>(static_cast<F&&>(f));
    }
}

// ---------------- kernel 1: fold coefficients ----------------
// w[(l*7+s)*16 + 2k + {0,1}] = (re,im) of W[l][s][k].
// slot 0 = a[:,l] + b[:,l,0] + c[:,l,0]; slots 1..3 = b m=1..3; 4..6 = c m=1..3.
__global__ void prefold_kernel(
    const float* __restrict__ a_re, const float* __restrict__ a_im,
    const float* __restrict__ b_re, const float* __restrict__ b_im,
    const float* __restrict__ c_re, const float* __restrict__ c_im,
    float* __restrict__ w)
{
    int idx = threadIdx.x;
    if (idx >= 448) return;
    int l = idx / 56;
    int rem = idx - l * 56;
    int s = rem >> 3;
    int k = rem & 7;
    int akl = k * 8 + l;                   // a[k][l]; b/c[k][l][m] = akl*4 + m
    float re, im;
    if (s == 0) {
        re = a_re[akl] + b_re[akl * 4] + c_re[akl * 4];
        im = a_im[akl] + b_im[akl * 4] + c_im[akl * 4];
    } else if (s <= 3) {
        re = b_re[akl * 4 + s];
        im = b_im[akl * 4 + s];
    } else {
        re = c_re[akl * 4 + (s - 3)];
        im = c_im[akl * 4 + (s - 3)];
    }
    w[idx * 2]     = re;
    w[idx * 2 + 1] = im;
}

// ---------------- kernel 2: main GMP ----------------
// y[n] = sum_L x[n-L] * sum_s P_{L,s}(r[n-L+d(s)]),  d: 0,-1,-2,-3,+1,+2,+3
// Wave w: lags {2w, 2w+1}; lane: samples {2*s2, 2*s2+1}.
// Coefficient s_loads batched in 4-slot / 3-slot clusters (<=64 SGPRs live)
// so each unordered-SMEM lgkmcnt(0) drain is amortized over ~4 slots of FMA.
__global__ __launch_bounds__(BLOCK) void gmp_kernel(
    const float* __restrict__ x,
    const float* __restrict__ wbuf,        // folded coefficients (896 floats)
    float* __restrict__ out, int N)
{
    __shared__ float2 sxc[SIG];
    __shared__ float sab[SIG];
    __shared__ float2 part[4][SPB];

    const int t = threadIdx.x;
    const int n0 = blockIdx.x * SPB;

    // ---- stage signal + envelope with clipped halo (single pass) ----
    const float2* x2 = (const float2*)x;
    if (t < SIG) {
        int g = n0 - HALO_LO + t;
        g = max(0, min(N - 1, g));
        float2 v = x2[g];
        sxc[t] = v;
        sab[t] = __builtin_amdgcn_sqrtf(fmaf(v.x, v.x, v.y * v.y));
    }
    __syncthreads();

    const int s2 = t & 63;                                   // sample lane
    const int wv = __builtin_amdgcn_readfirstlane(t >> 6);   // wave id 0..3
    // constant-AS view of this wave's 14 slots (uniform base)
    auto cw = (cptr<const float>)(unsigned long long)(wbuf + wv * 224);

    // window: rv[i] = |x| at smem index rb + i, i = 0..8
    const int rb = 2 * s2 + 6 - 2 * wv;
    float rv[9];
    unroll_for<0, 9>([&](auto I) { rv[I.value] = sab[rb + I.value]; });
    float2 xv[3];                  // x at smem index rb + 3 + i
    unroll_for<0, 3>([&](auto I) { xv[I.value] = sxc[rb + 3 + I.value]; });

    float y0r = 0.f, y0i = 0.f, y1r = 0.f, y1i = 0.f;

    unroll_for<0, 2>([&](auto LL) {
        constexpr int ll = LL.value;       // local lag: L = 2*wv + ll
        v2f S0 = {0.f, 0.f}, S1 = {0.f, 0.f};

        unroll_for<0, 2>([&](auto Pc) {    // phase 0: slots 0-3, phase 1: 4-6
            constexpr int ph = Pc.value;
            constexpr int sb = ph ? 4 : 0;
            constexpr int cnt = ph ? 3 : 4;

            // ---- batched uniform coefficient fetch: one s_load cluster ----
            v2f wk[4][8];
            unroll_for<0, cnt>([&](auto J) {
                constexpr int off = (ll * 7 + sb + J.value) * 16;
                unroll_for<0, 8>([&](auto K) {
                    wk[J.value][K.value] =
                        v2f{cw[off + 2 * K.value], cw[off + 2 * K.value + 1]};
                });
            });

            // ---- compute the batch ----
            unroll_for<0, cnt>([&](auto J) {
                constexpr int s = sb + J.value;
                constexpr int d = (s == 0) ? 0 : ((s <= 3) ? -s : (s - 3));
                const float r0 = rv[4 - ll + d];
                const float r1 = rv[5 - ll + d];
                const v2f rr0 = {r0, r0};
                const v2f rr1 = {r1, r1};
                v2f acc0 = wk[J.value][7];
                v2f acc1 = acc0;
                unroll_for<0, 7>([&](auto Kc) {
                    constexpr int k = 6 - Kc.value;
                    const v2f c = wk[J.value][k];
                    acc0 = __builtin_elementwise_fma(acc0, rr0, c);
                    acc1 = __builtin_elementwise_fma(acc1, rr1, c);
                });
                S0 += acc0;
                S1 += acc1;
            });
        });

        {
            const float xre = xv[1 - ll].x, xim = xv[1 - ll].y;
            y0r = fmaf(xre, S0.x, fmaf(-xim, S0.y, y0r));
            y0i = fmaf(xre, S0.y, fmaf( xim, S0.x, y0i));
        }
        {
            const float xre = xv[2 - ll].x, xim = xv[2 - ll].y;
            y1r = fmaf(xre, S1.x, fmaf(-xim, S1.y, y1r));
            y1i = fmaf(xre, S1.y, fmaf( xim, S1.x, y1i));
        }
    });

    part[wv][2 * s2]     = make_float2(y0r, y0i);
    part[wv][2 * s2 + 1] = make_float2(y1r, y1i);
    __syncthreads();

    if (t < SPB) {
        float2 p0 = part[0][t];
        float2 p1 = part[1][t];
        float2 p2 = part[2][t];
        float2 p3 = part[3][t];
        float2 r;
        r.x = (p0.x + p1.x) + (p2.x + p3.x);
        r.y = (p0.y + p1.y) + (p2.y + p3.y);
        const int n = n0 + t;
        if (n < N) ((float2*)out)[n] = r;
    }
}

extern "C" void kernel_launch(void* const* d_in, const int* in_sizes, int n_in,
                              void* d_out, int out_size, void* d_ws, size_t ws_size,
                              hipStream_t stream) {
    const float* x    = (const float*)d_in[0];
    const float* a_re = (const float*)d_in[1];
    const float* a_im = (const float*)d_in[2];
    const float* b_re = (const float*)d_in[3];
    const float* b_im = (const float*)d_in[4];
    const float* c_re = (const float*)d_in[5];
    const float* c_im = (const float*)d_in[6];
    float* out = (float*)d_out;
    float* w   = (float*)d_ws;             // 896 floats = 3584 bytes used

    int N = in_sizes[0] / 2;
    prefold_kernel<<<1, 448, 0, stream>>>(a_re, a_im, b_re, b_im, c_re, c_im, w);
    int grid = (N + SPB - 1) / SPB;        // 2048 blocks
    gmp_kernel<<<grid, BLOCK, 0, stream>>>(x, w, out, N);
}